// Round 3
// baseline (292.474 us; speedup 1.0000x reference)
//
#include <hip/hip_runtime.h>

// Problem constants
constexpr int Bb = 1024;   // batch
constexpr int Ii = 256;    // in features
constexpr int Oo = 256;    // out features
constexpr int Kk = 128;    // knots
constexpr int NCH = 8;     // i-chunks (XCD-aligned)

typedef unsigned short u16;
typedef unsigned int u32;
typedef u16 ushort8v __attribute__((ext_vector_type(8)));
typedef float f4v __attribute__((ext_vector_type(4)));

__device__ __forceinline__ float bf16u_to_f(u16 u) {
    union { u32 ui; float f; } c;
    c.ui = ((u32)u) << 16;
    return c.f;
}
__device__ __forceinline__ u16 f_to_bf16(float f) {  // round-to-nearest-even
    union { float f; u32 u; } c; c.f = f;
    u32 r = c.u + 0x7fffu + ((c.u >> 16) & 1u);
    return (u16)(r >> 16);
}

// Kernel A: permute+scale Cs[o][i][k] -> Cp[i][k][o] bf16 via LDS transpose.
// XCD-aligned numbering (chunk = blk & 7): chunk c's 2 MB Cp slice is written
// by XCD c and stays L2-resident for kmain's gathers. cs reads non-temporal
// (32 MB read-once stream must not evict cp from the 4 MB per-XCD L2).
// Tails: blocks <256 transpose wbase -> wt; block 512 zeroes the b-tile
// counters used by kmain's last-block reduction (re-zeroed EVERY launch).
__global__ __launch_bounds__(256) void kperm(const float* __restrict__ cs,
                                             const float* __restrict__ scale,
                                             const float* __restrict__ wbase,
                                             u16* __restrict__ cp,
                                             float* __restrict__ wt,
                                             int* __restrict__ cnt) {
    __shared__ u16 T[128 * 66];       // [o_local][k_local], pitch 66
    int blk = blockIdx.x;
    int chunk = blk & 7;
    int sub = blk >> 3;               // 0..127
    int i  = chunk * 32 + (sub & 31); // i within this XCD's chunk
    int oh = (sub >> 5) & 1, kh = (sub >> 6) & 1;
    int o0 = oh << 7, kb = kh << 6;
    int t = threadIdx.x;

    // Phase 1: load Cs rows (float4 along k, nt), scale, bf16 -> LDS
    {
        int c4 = t & 15;              // float4 index within the 64-k half
        int rb = t >> 4;              // 0..15
        const f4v* cs4 = (const f4v*)cs;
#pragma unroll
        for (int p = 0; p < 8; ++p) {
            int r = p * 16 + rb;      // o_local 0..127
            int o = o0 + r;
            float sc = scale[o * Ii + i];
            f4v val = __builtin_nontemporal_load(
                &cs4[(size_t)(o * Ii + i) * (Kk / 4) + kh * 16 + c4]);
            int kl = c4 * 4;
            T[r * 66 + kl + 0] = f_to_bf16(val.x * sc);
            T[r * 66 + kl + 1] = f_to_bf16(val.y * sc);
            T[r * 66 + kl + 2] = f_to_bf16(val.z * sc);
            T[r * 66 + kl + 3] = f_to_bf16(val.w * sc);
        }
    }
    __syncthreads();
    // Phase 2: write Cp[i][kb+kl][o0..o0+128], lanes <-> o (u32 = 2 o).
    {
        int og = t & 63;              // o-pair index
        int kg = t >> 6;              // 0..3, 16 k-rows each
#pragma unroll
        for (int m = 0; m < 16; ++m) {
            int kl = kg * 16 + m;
            u32 lo = T[(og * 2) * 66 + kl];
            u32 hi = T[(og * 2 + 1) * 66 + kl];
            *(u32*)&cp[((size_t)i * Kk + kb + kl) * Oo + o0 + og * 2] = lo | (hi << 16);
        }
    }
    // Tail A: Wt[i][o] = W[o][i] (65536 elems across blocks 0..255)
    if (blk < 256) {
        int gid = blk * 256 + t;
        wt[gid] = __builtin_nontemporal_load(&wbase[(gid & 255) * Ii + (gid >> 8)]);
    }
    // Tail B: zero the 128 per-b-tile arrival counters for kmain
    if (blk == 512 && t < 128) cnt[t] = 0;
}

// Kernel B: main accumulation + fused last-block reduction.
// 1024 blocks = 128 b-tiles x 8 i-chunks; 4 blocks/CU (LDS 36 KB).
// NEW thread partition vs R1: thread = 1 b x 8 o (was 2 b x 4 o) ->
//   * spline gathers per i-iter: 2 x 16 B ushort8 (was 4 x 8 B) — half the
//     gather instructions, each wave gather = 2 contiguous 512 B rows.
//   * w in two split LDS arrays wA/wB -> both reads 16 B/lane contiguous,
//     conflict-free.
// Reduction fused via per-b-tile atomicAdd counter: 8th arriving block sums
// the 8 chunk partials + bias -> out (no kreduce dispatch, no launch gap).
__global__ __launch_bounds__(256, 4) void kmain(const float* __restrict__ x,
                                                const char* __restrict__ cpb,
                                                const float* __restrict__ wt,
                                                float4* __restrict__ part4,
                                                int* __restrict__ cnt,
                                                const float4* __restrict__ bias4,
                                                float4* __restrict__ out4) {
    __shared__ float4 sf[256];           // [il][bl] : 32 i x 8 b    (4 KB)
    __shared__ float4 wA[32 * 32];       // [m][oq] = w[o=8oq..+3]  (16 KB)
    __shared__ float4 wB[32 * 32];       // [m][oq] = w[o=8oq+4..+7](16 KB)
    __shared__ int lastFlag;
    int t = threadIdx.x;
    int blk = blockIdx.x;
    int chunk = blk & (NCH - 1);
    int bt = blk >> 3;                   // b-tile 0..127
    int b0 = bt << 3;
    int i0 = chunk << 5;                 // 32 i per chunk

    {                                    // prep: 1 (b,i) value per thread
        int il = t & 31, bl = t >> 5;    // coalesced x reads along il
        float xv = __builtin_nontemporal_load(
            &x[(size_t)(b0 + bl) * Ii + i0 + il]);
        float e2 = __expf(2.f * xv);
        float p = 1.f - 2.f / (e2 + 1.f);   // tanh
        float s = p / (1.f + __expf(-p));   // silu(p)
        float c = fminf(fmaxf(p, -1.f), 1.f);
        float scaled = (c + 1.f) * ((float)(Kk - 1) * 0.5f);
        int l = (int)floorf(scaled);
        l = min(max(l, 0), Kk - 1);
        int rr = min(l + 1, Kk - 1);
        float4 v;
        v.x = scaled - (float)l;             // frac
        v.y = s;                             // silu
        v.z = __int_as_float(l * (Oo * 2));  // byte ofs, left row in [k][o] slab
        v.w = __int_as_float(rr * (Oo * 2)); // byte ofs, right row
        sf[il * 8 + bl] = v;
    }
    {                                    // stage w rows into split arrays
        int j = t & 31, mr = t >> 5;     // j = o-octet, 8 m-rows per pass
#pragma unroll
        for (int p = 0; p < 4; ++p) {
            int m = p * 8 + mr;
            const float* src = wt + (size_t)(i0 + m) * Oo + j * 8;
            wA[m * 32 + j] = *(const float4*)(src);
            wB[m * 32 + j] = *(const float4*)(src + 4);
        }
    }
    __syncthreads();                     // block-local: sf/wA/wB ready

    int oq = t & 31;                     // o = oq*8 .. oq*8+7
    int bl = t >> 5;                     // b = b0 + bl
    float a0=0.f,a1=0.f,a2=0.f,a3=0.f,a4=0.f,a5=0.f,a6=0.f,a7=0.f;
    const char* cbase = cpb + (size_t)i0 * (Kk * Oo * 2) + oq * 16;

#pragma unroll 4
    for (int m = 0; m < 32; ++m) {
        float4 v = sf[m * 8 + bl];                   // LDS broadcast (8 addrs)
        float4 wa = wA[m * 32 + oq];                 // 16 B/lane contiguous
        float4 wb = wB[m * 32 + oq];
        const char* ci = cbase + (size_t)m * (Kk * Oo * 2);
        ushort8v cl = *(const ushort8v*)(ci + __float_as_int(v.z));  // 16 B gather
        ushort8v cr = *(const ushort8v*)(ci + __float_as_int(v.w));  // 16 B gather
        float f = v.x, g = 1.f - v.x, s = v.y;
        a0 = fmaf(s, wa.x, a0); a1 = fmaf(s, wa.y, a1);
        a2 = fmaf(s, wa.z, a2); a3 = fmaf(s, wa.w, a3);
        a4 = fmaf(s, wb.x, a4); a5 = fmaf(s, wb.y, a5);
        a6 = fmaf(s, wb.z, a6); a7 = fmaf(s, wb.w, a7);
        a0 = fmaf(g, bf16u_to_f(cl[0]), a0); a0 = fmaf(f, bf16u_to_f(cr[0]), a0);
        a1 = fmaf(g, bf16u_to_f(cl[1]), a1); a1 = fmaf(f, bf16u_to_f(cr[1]), a1);
        a2 = fmaf(g, bf16u_to_f(cl[2]), a2); a2 = fmaf(f, bf16u_to_f(cr[2]), a2);
        a3 = fmaf(g, bf16u_to_f(cl[3]), a3); a3 = fmaf(f, bf16u_to_f(cr[3]), a3);
        a4 = fmaf(g, bf16u_to_f(cl[4]), a4); a4 = fmaf(f, bf16u_to_f(cr[4]), a4);
        a5 = fmaf(g, bf16u_to_f(cl[5]), a5); a5 = fmaf(f, bf16u_to_f(cr[5]), a5);
        a6 = fmaf(g, bf16u_to_f(cl[6]), a6); a6 = fmaf(f, bf16u_to_f(cr[6]), a6);
        a7 = fmaf(g, bf16u_to_f(cl[7]), a7); a7 = fmaf(f, bf16u_to_f(cr[7]), a7);
    }

    size_t cstride = (size_t)(Bb * Oo / 4);
    {
        float4 r0; r0.x=a0; r0.y=a1; r0.z=a2; r0.w=a3;
        float4 r1; r1.x=a4; r1.y=a5; r1.z=a6; r1.w=a7;
        size_t pb = (size_t)chunk * cstride + (size_t)(b0 + bl) * (Oo / 4) + oq * 2;
        part4[pb]     = r0;
        part4[pb + 1] = r1;
    }

    // ---- fused reduction: 8th block to arrive on this b-tile sums it ----
    __threadfence();                     // release: partials device-visible
    if (t == 0) lastFlag = (atomicAdd(&cnt[bt], 1) == NCH - 1);
    __syncthreads();
    if (lastFlag) {
        __threadfence();                 // acquire: invalidate stale lines
#pragma unroll
        for (int q = 0; q < 2; ++q) {
            int gid = bt * 512 + q * 256 + t;        // = b*64 + o4 within tile
            const f4v* p = (const f4v*)(part4 + gid);
            f4v s4 = __builtin_nontemporal_load(p);
#pragma unroll
            for (int c = 1; c < NCH; ++c) {
                f4v vv = __builtin_nontemporal_load(p + (size_t)c * cstride);
                s4.x += vv.x; s4.y += vv.y; s4.z += vv.z; s4.w += vv.w;
            }
            float4 bv = bias4[gid & 63];
            float4 o;
            o.x = s4.x + bv.x; o.y = s4.y + bv.y;
            o.z = s4.z + bv.z; o.w = s4.w + bv.w;
            out4[gid] = o;
        }
    }
}

extern "C" void kernel_launch(void* const* d_in, const int* in_sizes, int n_in,
                              void* d_out, int out_size, void* d_ws, size_t ws_size,
                              hipStream_t stream) {
    const float* x     = (const float*)d_in[0];
    const float* wbase = (const float*)d_in[1];
    const float* coeff = (const float*)d_in[2];
    const float* scale = (const float*)d_in[3];
    const float* bias  = (const float*)d_in[4];
    float4* out4 = (float4*)d_out;

    char* ws = (char*)d_ws;
    u16*    cp    = (u16*)ws;                             // 16 MB   @ 0
    float*  wt    = (float*)(ws + (16u << 20));           // 256 KB  @ 16M
    int*    cnt   = (int*)(ws + (16u << 20) + (512u << 10)); // 512 B @ 16.5M
    float4* part4 = (float4*)(ws + (17u << 20));          // 8 MB    @ 17M

    kperm<<<1024, 256, 0, stream>>>(coeff, scale, wbase, cp, wt, cnt);
    kmain<<<1024, 256, 0, stream>>>(x, (const char*)cp, wt, part4, cnt,
                                    (const float4*)bias, out4);
}

// Round 4
// 155.466 us; speedup vs baseline: 1.8813x; 1.8813x over previous
//
#include <hip/hip_runtime.h>

// Problem constants
constexpr int Bb = 1024;   // batch
constexpr int Ii = 256;    // in features
constexpr int Oo = 256;    // out features
constexpr int Kk = 128;    // knots
constexpr int NCH = 8;     // i-chunks (XCD-aligned)

typedef unsigned short u16;
typedef unsigned int u32;
typedef u16 ushort8v __attribute__((ext_vector_type(8)));
typedef float f4v __attribute__((ext_vector_type(4)));

__device__ __forceinline__ float bf16u_to_f(u16 u) {
    union { u32 ui; float f; } c;
    c.ui = ((u32)u) << 16;
    return c.f;
}
__device__ __forceinline__ u16 f_to_bf16(float f) {  // round-to-nearest-even
    union { float f; u32 u; } c; c.f = f;
    u32 r = c.u + 0x7fffu + ((c.u >> 16) & 1u);
    return (u16)(r >> 16);
}

// Kernel A: permute+scale Cs[o][i][k] -> Cp[i][k][o] bf16 via LDS transpose.
// XCD-aligned numbering (chunk = blk & 7): chunk c's 2 MB Cp slice is written
// by XCD c and stays L2-resident for kmain's gathers. cs reads non-temporal
// (32 MB read-once stream must not evict cp from the 4 MB per-XCD L2).
// Tails: blocks <256 transpose wbase -> wt; blocks 256..511 init out = bias
// (kmain accumulates into out with atomics; re-init EVERY launch).
// NO device fences anywhere: kernel boundary is the coherence point.
__global__ __launch_bounds__(256) void kperm(const float* __restrict__ cs,
                                             const float* __restrict__ scale,
                                             const float* __restrict__ wbase,
                                             u16* __restrict__ cp,
                                             float* __restrict__ wt,
                                             const float4* __restrict__ bias4,
                                             float4* __restrict__ out4) {
    __shared__ u16 T[128 * 66];       // [o_local][k_local], pitch 66
    int blk = blockIdx.x;
    int chunk = blk & 7;
    int sub = blk >> 3;               // 0..127
    int i  = chunk * 32 + (sub & 31); // i within this XCD's chunk
    int oh = (sub >> 5) & 1, kh = (sub >> 6) & 1;
    int o0 = oh << 7, kb = kh << 6;
    int t = threadIdx.x;

    // Phase 1: load Cs rows (float4 along k, nt), scale, bf16 -> LDS
    {
        int c4 = t & 15;              // float4 index within the 64-k half
        int rb = t >> 4;              // 0..15
        const f4v* cs4 = (const f4v*)cs;
#pragma unroll
        for (int p = 0; p < 8; ++p) {
            int r = p * 16 + rb;      // o_local 0..127
            int o = o0 + r;
            float sc = scale[o * Ii + i];
            f4v val = __builtin_nontemporal_load(
                &cs4[(size_t)(o * Ii + i) * (Kk / 4) + kh * 16 + c4]);
            int kl = c4 * 4;
            T[r * 66 + kl + 0] = f_to_bf16(val.x * sc);
            T[r * 66 + kl + 1] = f_to_bf16(val.y * sc);
            T[r * 66 + kl + 2] = f_to_bf16(val.z * sc);
            T[r * 66 + kl + 3] = f_to_bf16(val.w * sc);
        }
    }
    __syncthreads();
    // Phase 2: write Cp[i][kb+kl][o0..o0+128], lanes <-> o (u32 = 2 o).
    {
        int og = t & 63;              // o-pair index
        int kg = t >> 6;              // 0..3, 16 k-rows each
#pragma unroll
        for (int m = 0; m < 16; ++m) {
            int kl = kg * 16 + m;
            u32 lo = T[(og * 2) * 66 + kl];
            u32 hi = T[(og * 2 + 1) * 66 + kl];
            *(u32*)&cp[((size_t)i * Kk + kb + kl) * Oo + o0 + og * 2] = lo | (hi << 16);
        }
    }
    // Tail A: Wt[i][o] = W[o][i] (65536 elems across blocks 0..255)
    if (blk < 256) {
        int gid = blk * 256 + t;
        wt[gid] = __builtin_nontemporal_load(&wbase[(gid & 255) * Ii + (gid >> 8)]);
    }
    // Tail B: out[b][o] = bias[o] (blocks 256..511; kmain atomically adds)
    if (blk >= 256 && blk < 512) {
        int gid = (blk - 256) * 256 + t;       // float4 index = b*64 + o4
        out4[gid] = bias4[gid & 63];
    }
}

// Kernel B: main accumulation. 1024 blocks = 128 b-tiles x 8 i-chunks;
// 4 blocks/CU (LDS 36 KB). Thread = 1 b x 8 o:
//   * 2 x 16 B ushort8 gathers per i-iter; each half-wave gather is a
//     uniform-base contiguous 512 B row segment (perfectly coalesced).
//   * w staged in split wA/wB LDS arrays -> 16 B/lane conflict-free reads.
// Output: 8 fire-and-forget global atomicAdd f32 into out (pre-init'd to
// bias by kperm). Device-scope atomics are coherent WITHOUT fences; no
// part4 roundtrip, no kreduce dispatch, no L2-flush storm (R3 lesson).
__global__ __launch_bounds__(256, 4) void kmain(const float* __restrict__ x,
                                                const char* __restrict__ cpb,
                                                const float* __restrict__ wt,
                                                float* __restrict__ out) {
    __shared__ float4 sf[256];           // [il][bl] : 32 i x 8 b    (4 KB)
    __shared__ float4 wA[32 * 32];       // [m][oq] = w[o=8oq..+3]  (16 KB)
    __shared__ float4 wB[32 * 32];       // [m][oq] = w[o=8oq+4..+7](16 KB)
    int t = threadIdx.x;
    int blk = blockIdx.x;
    int chunk = blk & (NCH - 1);
    int bt = blk >> 3;                   // b-tile 0..127
    int b0 = bt << 3;
    int i0 = chunk << 5;                 // 32 i per chunk

    {                                    // prep: 1 (b,i) value per thread
        int il = t & 31, bl = t >> 5;    // coalesced x reads along il
        float xv = __builtin_nontemporal_load(
            &x[(size_t)(b0 + bl) * Ii + i0 + il]);
        float e2 = __expf(2.f * xv);
        float p = 1.f - 2.f / (e2 + 1.f);   // tanh
        float s = p / (1.f + __expf(-p));   // silu(p)
        float c = fminf(fmaxf(p, -1.f), 1.f);
        float scaled = (c + 1.f) * ((float)(Kk - 1) * 0.5f);
        int l = (int)floorf(scaled);
        l = min(max(l, 0), Kk - 1);
        int rr = min(l + 1, Kk - 1);
        float4 v;
        v.x = scaled - (float)l;             // frac
        v.y = s;                             // silu
        v.z = __int_as_float(l * (Oo * 2));  // byte ofs, left row in [k][o] slab
        v.w = __int_as_float(rr * (Oo * 2)); // byte ofs, right row
        sf[il * 8 + bl] = v;
    }
    {                                    // stage w rows into split arrays
        int j = t & 31, mr = t >> 5;     // j = o-octet, 8 m-rows per pass
#pragma unroll
        for (int p = 0; p < 4; ++p) {
            int m = p * 8 + mr;
            const float* src = wt + (size_t)(i0 + m) * Oo + j * 8;
            wA[m * 32 + j] = *(const float4*)(src);
            wB[m * 32 + j] = *(const float4*)(src + 4);
        }
    }
    __syncthreads();                     // block-local: sf/wA/wB ready

    int oq = t & 31;                     // o = oq*8 .. oq*8+7
    int bl = t >> 5;                     // b = b0 + bl
    float a0=0.f,a1=0.f,a2=0.f,a3=0.f,a4=0.f,a5=0.f,a6=0.f,a7=0.f;
    const char* cbase = cpb + (size_t)i0 * (Kk * Oo * 2) + oq * 16;

#pragma unroll 8
    for (int m = 0; m < 32; ++m) {
        float4 v = sf[m * 8 + bl];                   // LDS broadcast (2 addrs/wave)
        float4 wa = wA[m * 32 + oq];                 // 16 B/lane contiguous
        float4 wb = wB[m * 32 + oq];
        const char* ci = cbase + (size_t)m * (Kk * Oo * 2);
        ushort8v cl = *(const ushort8v*)(ci + __float_as_int(v.z));  // 16 B gather
        ushort8v cr = *(const ushort8v*)(ci + __float_as_int(v.w));  // 16 B gather
        float f = v.x, g = 1.f - v.x, s = v.y;
        a0 = fmaf(s, wa.x, a0); a1 = fmaf(s, wa.y, a1);
        a2 = fmaf(s, wa.z, a2); a3 = fmaf(s, wa.w, a3);
        a4 = fmaf(s, wb.x, a4); a5 = fmaf(s, wb.y, a5);
        a6 = fmaf(s, wb.z, a6); a7 = fmaf(s, wb.w, a7);
        a0 = fmaf(g, bf16u_to_f(cl[0]), a0); a0 = fmaf(f, bf16u_to_f(cr[0]), a0);
        a1 = fmaf(g, bf16u_to_f(cl[1]), a1); a1 = fmaf(f, bf16u_to_f(cr[1]), a1);
        a2 = fmaf(g, bf16u_to_f(cl[2]), a2); a2 = fmaf(f, bf16u_to_f(cr[2]), a2);
        a3 = fmaf(g, bf16u_to_f(cl[3]), a3); a3 = fmaf(f, bf16u_to_f(cr[3]), a3);
        a4 = fmaf(g, bf16u_to_f(cl[4]), a4); a4 = fmaf(f, bf16u_to_f(cr[4]), a4);
        a5 = fmaf(g, bf16u_to_f(cl[5]), a5); a5 = fmaf(f, bf16u_to_f(cr[5]), a5);
        a6 = fmaf(g, bf16u_to_f(cl[6]), a6); a6 = fmaf(f, bf16u_to_f(cr[6]), a6);
        a7 = fmaf(g, bf16u_to_f(cl[7]), a7); a7 = fmaf(f, bf16u_to_f(cr[7]), a7);
    }

    // fire-and-forget accumulation into out (pre-init'd to bias by kperm)
    float* ob = out + (size_t)(b0 + bl) * Oo + oq * 8;
    atomicAdd(ob + 0, a0); atomicAdd(ob + 1, a1);
    atomicAdd(ob + 2, a2); atomicAdd(ob + 3, a3);
    atomicAdd(ob + 4, a4); atomicAdd(ob + 5, a5);
    atomicAdd(ob + 6, a6); atomicAdd(ob + 7, a7);
}

extern "C" void kernel_launch(void* const* d_in, const int* in_sizes, int n_in,
                              void* d_out, int out_size, void* d_ws, size_t ws_size,
                              hipStream_t stream) {
    const float* x     = (const float*)d_in[0];
    const float* wbase = (const float*)d_in[1];
    const float* coeff = (const float*)d_in[2];
    const float* scale = (const float*)d_in[3];
    const float* bias  = (const float*)d_in[4];
    float* out = (float*)d_out;

    char* ws = (char*)d_ws;
    u16*   cp = (u16*)ws;                     // 16 MB   @ 0
    float* wt = (float*)(ws + (16u << 20));   // 256 KB  @ 16M

    kperm<<<1024, 256, 0, stream>>>(coeff, scale, wbase, cp, wt,
                                    (const float4*)bias, (float4*)out);
    kmain<<<1024, 256, 0, stream>>>(x, (const char*)cp, wt, out);
}

// Round 5
// 110.808 us; speedup vs baseline: 2.6395x; 1.4030x over previous
//
#include <hip/hip_runtime.h>

// Problem constants
constexpr int Bb = 1024;   // batch
constexpr int Ii = 256;    // in features
constexpr int Oo = 256;    // out features
constexpr int Kk = 128;    // knots
constexpr int NCH = 8;     // i-chunks (XCD-aligned)

typedef unsigned short u16;
typedef unsigned int u32;
typedef u16 ushort8v __attribute__((ext_vector_type(8)));
typedef float f4v __attribute__((ext_vector_type(4)));

__device__ __forceinline__ float bf16u_to_f(u16 u) {
    union { u32 ui; float f; } c;
    c.ui = ((u32)u) << 16;
    return c.f;
}
__device__ __forceinline__ u16 f_to_bf16(float f) {  // round-to-nearest-even
    union { float f; u32 u; } c; c.f = f;
    u32 r = c.u + 0x7fffu + ((c.u >> 16) & 1u);
    return (u16)(r >> 16);
}

// Kernel A: permute+scale Cs[o][i][k] -> Cp[i][k][o] bf16 via LDS transpose.
// XCD-aligned numbering (chunk = blk & 7): chunk c's 2 MB Cp slice is written
// by XCD c and stays cache-resident for kmain's gathers (R4 counters: kmain
// FETCH 8.9 MB vs 256 MB gather volume -> locality verified).
// cs reads non-temporal (32 MB read-once stream must not evict cp).
// Tail: blocks <256 transpose wbase -> wt.
// NO fences, NO atomics (R3: in-kernel device fences = L2 flush storm;
// R4: cross-XCD shared-line atomics = HBM-side RMW storm). Kernel boundary
// is the coherence point.
__global__ __launch_bounds__(256) void kperm(const float* __restrict__ cs,
                                             const float* __restrict__ scale,
                                             const float* __restrict__ wbase,
                                             u16* __restrict__ cp,
                                             float* __restrict__ wt) {
    __shared__ u16 T[128 * 66];       // [o_local][k_local], pitch 66
    int blk = blockIdx.x;
    int chunk = blk & 7;
    int sub = blk >> 3;               // 0..127
    int i  = chunk * 32 + (sub & 31); // i within this XCD's chunk
    int oh = (sub >> 5) & 1, kh = (sub >> 6) & 1;
    int o0 = oh << 7, kb = kh << 6;
    int t = threadIdx.x;

    // Phase 1: load Cs rows (float4 along k, nt), scale, bf16 -> LDS
    {
        int c4 = t & 15;              // float4 index within the 64-k half
        int rb = t >> 4;              // 0..15
        const f4v* cs4 = (const f4v*)cs;
#pragma unroll
        for (int p = 0; p < 8; ++p) {
            int r = p * 16 + rb;      // o_local 0..127
            int o = o0 + r;
            float sc = scale[o * Ii + i];
            f4v val = __builtin_nontemporal_load(
                &cs4[(size_t)(o * Ii + i) * (Kk / 4) + kh * 16 + c4]);
            int kl = c4 * 4;
            T[r * 66 + kl + 0] = f_to_bf16(val.x * sc);
            T[r * 66 + kl + 1] = f_to_bf16(val.y * sc);
            T[r * 66 + kl + 2] = f_to_bf16(val.z * sc);
            T[r * 66 + kl + 3] = f_to_bf16(val.w * sc);
        }
    }
    __syncthreads();
    // Phase 2: write Cp[i][kb+kl][o0..o0+128], lanes <-> o (u32 = 2 o).
    {
        int og = t & 63;              // o-pair index
        int kg = t >> 6;              // 0..3, 16 k-rows each
#pragma unroll
        for (int m = 0; m < 16; ++m) {
            int kl = kg * 16 + m;
            u32 lo = T[(og * 2) * 66 + kl];
            u32 hi = T[(og * 2 + 1) * 66 + kl];
            *(u32*)&cp[((size_t)i * Kk + kb + kl) * Oo + o0 + og * 2] = lo | (hi << 16);
        }
    }
    // Tail: Wt[i][o] = W[o][i] (65536 elems across blocks 0..255)
    if (blk < 256) {
        int gid = blk * 256 + t;
        wt[gid] = __builtin_nontemporal_load(&wbase[(gid & 255) * Ii + (gid >> 8)]);
    }
}

// Kernel B: main accumulation. 1024 blocks = 128 b-tiles x 8 i-chunks;
// 4 blocks/CU (LDS 36 KB). Thread = 1 b x 8 o:
//   * 2 x 16 B ushort8 gathers per i-iter; each half-wave gather is a
//     uniform-base contiguous 512 B row segment (perfectly coalesced).
//   * w staged in split wA/wB LDS arrays -> 16 B/lane conflict-free reads.
//   * sf layout [bl][il]: write stride 16 B/lane (conflict-free; the old
//     [il][bl] write was a 32-way bank conflict = the 229K counter).
// Output: plain float4 stores to per-XCD-private part4 regions; kreduce
// sums after the kernel-boundary coherence point.
__global__ __launch_bounds__(256, 4) void kmain(const float* __restrict__ x,
                                                const char* __restrict__ cpb,
                                                const float* __restrict__ wt,
                                                float4* __restrict__ part4) {
    __shared__ float4 sf[256];           // [bl][il] : 8 b x 32 i    (4 KB)
    __shared__ float4 wA[32 * 32];       // [m][oq] = w[o=8oq..+3]  (16 KB)
    __shared__ float4 wB[32 * 32];       // [m][oq] = w[o=8oq+4..+7](16 KB)
    int t = threadIdx.x;
    int blk = blockIdx.x;
    int chunk = blk & (NCH - 1);
    int bt = blk >> 3;                   // b-tile 0..127
    int b0 = bt << 3;
    int i0 = chunk << 5;                 // 32 i per chunk

    {                                    // prep: 1 (b,i) value per thread
        int il = t & 31, bl = t >> 5;    // coalesced x reads along il
        float xv = __builtin_nontemporal_load(
            &x[(size_t)(b0 + bl) * Ii + i0 + il]);
        float e2 = __expf(2.f * xv);
        float p = 1.f - 2.f / (e2 + 1.f);   // tanh
        float s = p / (1.f + __expf(-p));   // silu(p)
        float c = fminf(fmaxf(p, -1.f), 1.f);
        float scaled = (c + 1.f) * ((float)(Kk - 1) * 0.5f);
        int l = (int)floorf(scaled);
        l = min(max(l, 0), Kk - 1);
        int rr = min(l + 1, Kk - 1);
        float4 v;
        v.x = scaled - (float)l;             // frac
        v.y = s;                             // silu
        v.z = __int_as_float(l * (Oo * 2));  // byte ofs, left row in [k][o] slab
        v.w = __int_as_float(rr * (Oo * 2)); // byte ofs, right row
        sf[bl * 32 + il] = v;                // 16 B/lane stride: conflict-free
    }
    {                                    // stage w rows into split arrays
        int j = t & 31, mr = t >> 5;     // j = o-octet, 8 m-rows per pass
#pragma unroll
        for (int p = 0; p < 4; ++p) {
            int m = p * 8 + mr;
            const float* src = wt + (size_t)(i0 + m) * Oo + j * 8;
            wA[m * 32 + j] = *(const float4*)(src);
            wB[m * 32 + j] = *(const float4*)(src + 4);
        }
    }
    __syncthreads();                     // block-local: sf/wA/wB ready

    int oq = t & 31;                     // o = oq*8 .. oq*8+7
    int bl = t >> 5;                     // b = b0 + bl
    float a0=0.f,a1=0.f,a2=0.f,a3=0.f,a4=0.f,a5=0.f,a6=0.f,a7=0.f;
    const char* cbase = cpb + (size_t)i0 * (Kk * Oo * 2) + oq * 16;

#pragma unroll 8
    for (int m = 0; m < 32; ++m) {
        float4 v = sf[bl * 32 + m];                  // broadcast (2 addrs/wave)
        float4 wa = wA[m * 32 + oq];                 // 16 B/lane contiguous
        float4 wb = wB[m * 32 + oq];
        const char* ci = cbase + (size_t)m * (Kk * Oo * 2);
        ushort8v cl = *(const ushort8v*)(ci + __float_as_int(v.z));  // 16 B gather
        ushort8v cr = *(const ushort8v*)(ci + __float_as_int(v.w));  // 16 B gather
        float f = v.x, g = 1.f - v.x, s = v.y;
        a0 = fmaf(s, wa.x, a0); a1 = fmaf(s, wa.y, a1);
        a2 = fmaf(s, wa.z, a2); a3 = fmaf(s, wa.w, a3);
        a4 = fmaf(s, wb.x, a4); a5 = fmaf(s, wb.y, a5);
        a6 = fmaf(s, wb.z, a6); a7 = fmaf(s, wb.w, a7);
        a0 = fmaf(g, bf16u_to_f(cl[0]), a0); a0 = fmaf(f, bf16u_to_f(cr[0]), a0);
        a1 = fmaf(g, bf16u_to_f(cl[1]), a1); a1 = fmaf(f, bf16u_to_f(cr[1]), a1);
        a2 = fmaf(g, bf16u_to_f(cl[2]), a2); a2 = fmaf(f, bf16u_to_f(cr[2]), a2);
        a3 = fmaf(g, bf16u_to_f(cl[3]), a3); a3 = fmaf(f, bf16u_to_f(cr[3]), a3);
        a4 = fmaf(g, bf16u_to_f(cl[4]), a4); a4 = fmaf(f, bf16u_to_f(cr[4]), a4);
        a5 = fmaf(g, bf16u_to_f(cl[5]), a5); a5 = fmaf(f, bf16u_to_f(cr[5]), a5);
        a6 = fmaf(g, bf16u_to_f(cl[6]), a6); a6 = fmaf(f, bf16u_to_f(cr[6]), a6);
        a7 = fmaf(g, bf16u_to_f(cl[7]), a7); a7 = fmaf(f, bf16u_to_f(cr[7]), a7);
    }

    size_t cstride = (size_t)(Bb * Oo / 4);
    float4 r0; r0.x=a0; r0.y=a1; r0.z=a2; r0.w=a3;
    float4 r1; r1.x=a4; r1.y=a5; r1.z=a6; r1.w=a7;
    size_t pb = (size_t)chunk * cstride + (size_t)(b0 + bl) * (Oo / 4) + oq * 2;
    part4[pb]     = r0;
    part4[pb + 1] = r1;
}

// Kernel C: out[b][o] = bias[o] + sum_c partial[c][b][o]. 256 blocks.
__global__ __launch_bounds__(256) void kreduce(const float4* __restrict__ part4,
                                               const float4* __restrict__ bias4,
                                               float4* __restrict__ out4) {
    int gid = blockIdx.x * 256 + threadIdx.x;     // = b*64 + o4
    const f4v* p = (const f4v*)(part4 + gid);
    f4v s = __builtin_nontemporal_load(p);
#pragma unroll
    for (int c = 1; c < NCH; ++c) {
        f4v v = __builtin_nontemporal_load(p + (size_t)c * (Bb * Oo / 4));
        s.x += v.x; s.y += v.y; s.z += v.z; s.w += v.w;
    }
    float4 bv = ((const float4*)bias4)[gid & 63];
    float4 o;
    o.x = s.x + bv.x; o.y = s.y + bv.y; o.z = s.z + bv.z; o.w = s.w + bv.w;
    out4[gid] = o;
}

extern "C" void kernel_launch(void* const* d_in, const int* in_sizes, int n_in,
                              void* d_out, int out_size, void* d_ws, size_t ws_size,
                              hipStream_t stream) {
    const float* x     = (const float*)d_in[0];
    const float* wbase = (const float*)d_in[1];
    const float* coeff = (const float*)d_in[2];
    const float* scale = (const float*)d_in[3];
    const float* bias  = (const float*)d_in[4];
    float* out = (float*)d_out;

    char* ws = (char*)d_ws;
    u16*    cp    = (u16*)ws;                             // 16 MB  @ 0
    float*  wt    = (float*)(ws + (16u << 20));           // 256 KB @ 16M
    float4* part4 = (float4*)(ws + (17u << 20));          // 8 MB   @ 17M

    kperm<<<1024, 256, 0, stream>>>(coeff, scale, wbase, cp, wt);
    kmain<<<1024, 256, 0, stream>>>(x, (const char*)cp, wt, part4);
    kreduce<<<(Bb * Oo / 4) / 256, 256, 0, stream>>>(part4, (const float4*)bias, (float4*)out);
}

// Round 6
// 109.685 us; speedup vs baseline: 2.6665x; 1.0102x over previous
//
#include <hip/hip_runtime.h>

// Problem constants
constexpr int Bb = 1024;   // batch
constexpr int Ii = 256;    // in features
constexpr int Oo = 256;    // out features
constexpr int Kk = 128;    // knots
constexpr int NCH = 8;     // i-chunks (XCD-aligned)

typedef unsigned short u16;
typedef unsigned int u32;
typedef u16 ushort8v __attribute__((ext_vector_type(8)));
typedef float f4v __attribute__((ext_vector_type(4)));

__device__ __forceinline__ float bf16u_to_f(u16 u) {
    union { u32 ui; float f; } c;
    c.ui = ((u32)u) << 16;
    return c.f;
}
__device__ __forceinline__ u16 f_to_bf16(float f) {  // round-to-nearest-even
    union { float f; u32 u; } c; c.f = f;
    u32 r = c.u + 0x7fffu + ((c.u >> 16) & 1u);
    return (u16)(r >> 16);
}

// Kernel A: permute+scale Cs[o][i][k] -> Cp[i][k][o] bf16 via LDS transpose.
// XCD-aligned numbering (chunk = blk & 7): chunk c's 2 MB Cp slice is written
// by XCD c and stays cache-resident for kmain's gathers (R4 counters: kmain
// FETCH 8.9 MB vs 256 MB gather volume -> locality verified).
// cs reads non-temporal (32 MB read-once stream must not evict cp).
// Tail: blocks <256 transpose wbase -> wt.
// NO fences, NO atomics (R3: in-kernel device fences = L2 flush storm;
// R4: cross-XCD shared-line atomics = HBM-side RMW storm). Kernel boundary
// is the coherence point.
__global__ __launch_bounds__(256) void kperm(const float* __restrict__ cs,
                                             const float* __restrict__ scale,
                                             const float* __restrict__ wbase,
                                             u16* __restrict__ cp,
                                             float* __restrict__ wt) {
    __shared__ u16 T[128 * 66];       // [o_local][k_local], pitch 66
    int blk = blockIdx.x;
    int chunk = blk & 7;
    int sub = blk >> 3;               // 0..127
    int i  = chunk * 32 + (sub & 31); // i within this XCD's chunk
    int oh = (sub >> 5) & 1, kh = (sub >> 6) & 1;
    int o0 = oh << 7, kb = kh << 6;
    int t = threadIdx.x;

    // Phase 1: load Cs rows (float4 along k, nt), scale, bf16 -> LDS
    {
        int c4 = t & 15;              // float4 index within the 64-k half
        int rb = t >> 4;              // 0..15
        const f4v* cs4 = (const f4v*)cs;
#pragma unroll
        for (int p = 0; p < 8; ++p) {
            int r = p * 16 + rb;      // o_local 0..127
            int o = o0 + r;
            float sc = scale[o * Ii + i];
            f4v val = __builtin_nontemporal_load(
                &cs4[(size_t)(o * Ii + i) * (Kk / 4) + kh * 16 + c4]);
            int kl = c4 * 4;
            T[r * 66 + kl + 0] = f_to_bf16(val.x * sc);
            T[r * 66 + kl + 1] = f_to_bf16(val.y * sc);
            T[r * 66 + kl + 2] = f_to_bf16(val.z * sc);
            T[r * 66 + kl + 3] = f_to_bf16(val.w * sc);
        }
    }
    __syncthreads();
    // Phase 2: write Cp[i][kb+kl][o0..o0+128], lanes <-> o (u32 = 2 o).
    {
        int og = t & 63;              // o-pair index
        int kg = t >> 6;              // 0..3, 16 k-rows each
#pragma unroll
        for (int m = 0; m < 16; ++m) {
            int kl = kg * 16 + m;
            u32 lo = T[(og * 2) * 66 + kl];
            u32 hi = T[(og * 2 + 1) * 66 + kl];
            *(u32*)&cp[((size_t)i * Kk + kb + kl) * Oo + o0 + og * 2] = lo | (hi << 16);
        }
    }
    // Tail: Wt[i][o] = W[o][i] (65536 elems across blocks 0..255)
    if (blk < 256) {
        int gid = blk * 256 + t;
        wt[gid] = __builtin_nontemporal_load(&wbase[(gid & 255) * Ii + (gid >> 8)]);
    }
}

// Kernel B: main accumulation. 1024 blocks = 128 b-tiles x 8 i-chunks.
// R6 restructure for OCCUPANCY (R4 measured 24%: 4 blocks/CU couldn't hide
// ~200cyc L2 gather latency):
//   * no w LDS staging — wt rows read directly in-loop (coalesced float4,
//     block slice 32 KB = L1-resident; redundant LDS copy removed).
//   * LDS 36 KB -> 4 KB; __launch_bounds__(256,8) -> 8 blocks/CU, 32 w/CU.
//   * ZERO barriers: sf exchange is intra-half-wave (writer t=bl*32+il,
//     readers have t>>5==bl — same 32-lane group), so per-thread program
//     order + lgkmcnt suffice; waves run fully independent.
//   * thread = 1 b x 8 o: 2 x 16 B ushort8 gathers per i-iter; each
//     half-wave gather = contiguous 512 B row segment in the XCD-local
//     cp slice (R4: FETCH 8.9 MB vs 256 MB volume -> cache-hit verified).
__global__ __launch_bounds__(256, 8) void kmain(const float* __restrict__ x,
                                                const char* __restrict__ cpb,
                                                const float* __restrict__ wt,
                                                float4* __restrict__ part4) {
    __shared__ float4 sf[256];           // [bl][il] : 8 b x 32 i (4 KB)
    int t = threadIdx.x;
    int blk = blockIdx.x;
    int chunk = blk & (NCH - 1);
    int b0 = (blk >> 3) << 3;            // b-tile * 8
    int i0 = chunk << 5;                 // 32 i per chunk

    {                                    // prep: 1 (b,i) value per thread
        int il = t & 31, bl = t >> 5;    // coalesced x reads along il
        float xv = __builtin_nontemporal_load(
            &x[(size_t)(b0 + bl) * Ii + i0 + il]);
        float e2 = __expf(2.f * xv);
        float p = 1.f - 2.f / (e2 + 1.f);   // tanh
        float s = p / (1.f + __expf(-p));   // silu(p)
        float c = fminf(fmaxf(p, -1.f), 1.f);
        float scaled = (c + 1.f) * ((float)(Kk - 1) * 0.5f);
        int l = (int)floorf(scaled);
        l = min(max(l, 0), Kk - 1);
        int rr = min(l + 1, Kk - 1);
        float4 v;
        v.x = scaled - (float)l;             // frac
        v.y = s;                             // silu
        v.z = __int_as_float(l * (Oo * 2));  // byte ofs, left row in [k][o] slab
        v.w = __int_as_float(rr * (Oo * 2)); // byte ofs, right row
        sf[bl * 32 + il] = v;                // 16 B/lane stride: conflict-free
    }
    // no __syncthreads(): see header comment (intra-half-wave exchange).

    int oq = t & 31;                     // o = oq*8 .. oq*8+7
    int bl = t >> 5;                     // b = b0 + bl
    float a0=0.f,a1=0.f,a2=0.f,a3=0.f,a4=0.f,a5=0.f,a6=0.f,a7=0.f;
    const char* cbase = cpb + (size_t)i0 * (Kk * Oo * 2) + oq * 16;
    const float4* wrow = (const float4*)(wt + (size_t)i0 * Oo) + oq * 2;

#pragma unroll 2
    for (int m = 0; m < 32; ++m) {
        float4 v = sf[bl * 32 + m];                  // broadcast (2 addrs/wave)
        float4 wa = wrow[m * (Oo / 4)];              // wt[(i0+m)*Oo + oq*8..+3]
        float4 wb = wrow[m * (Oo / 4) + 1];          // ..+4..+7 (L1-resident)
        const char* ci = cbase + (size_t)m * (Kk * Oo * 2);
        ushort8v cl = *(const ushort8v*)(ci + __float_as_int(v.z));  // 16 B gather
        ushort8v cr = *(const ushort8v*)(ci + __float_as_int(v.w));  // 16 B gather
        float f = v.x, g = 1.f - v.x, s = v.y;
        a0 = fmaf(s, wa.x, a0); a1 = fmaf(s, wa.y, a1);
        a2 = fmaf(s, wa.z, a2); a3 = fmaf(s, wa.w, a3);
        a4 = fmaf(s, wb.x, a4); a5 = fmaf(s, wb.y, a5);
        a6 = fmaf(s, wb.z, a6); a7 = fmaf(s, wb.w, a7);
        a0 = fmaf(g, bf16u_to_f(cl[0]), a0); a0 = fmaf(f, bf16u_to_f(cr[0]), a0);
        a1 = fmaf(g, bf16u_to_f(cl[1]), a1); a1 = fmaf(f, bf16u_to_f(cr[1]), a1);
        a2 = fmaf(g, bf16u_to_f(cl[2]), a2); a2 = fmaf(f, bf16u_to_f(cr[2]), a2);
        a3 = fmaf(g, bf16u_to_f(cl[3]), a3); a3 = fmaf(f, bf16u_to_f(cr[3]), a3);
        a4 = fmaf(g, bf16u_to_f(cl[4]), a4); a4 = fmaf(f, bf16u_to_f(cr[4]), a4);
        a5 = fmaf(g, bf16u_to_f(cl[5]), a5); a5 = fmaf(f, bf16u_to_f(cr[5]), a5);
        a6 = fmaf(g, bf16u_to_f(cl[6]), a6); a6 = fmaf(f, bf16u_to_f(cr[6]), a6);
        a7 = fmaf(g, bf16u_to_f(cl[7]), a7); a7 = fmaf(f, bf16u_to_f(cr[7]), a7);
    }

    size_t cstride = (size_t)(Bb * Oo / 4);
    float4 r0; r0.x=a0; r0.y=a1; r0.z=a2; r0.w=a3;
    float4 r1; r1.x=a4; r1.y=a5; r1.z=a6; r1.w=a7;
    size_t pb = (size_t)chunk * cstride + (size_t)(b0 + bl) * (Oo / 4) + oq * 2;
    part4[pb]     = r0;
    part4[pb + 1] = r1;
}

// Kernel C: out[b][o] = bias[o] + sum_c partial[c][b][o]. 256 blocks.
__global__ __launch_bounds__(256) void kreduce(const float4* __restrict__ part4,
                                               const float4* __restrict__ bias4,
                                               float4* __restrict__ out4) {
    int gid = blockIdx.x * 256 + threadIdx.x;     // = b*64 + o4
    const f4v* p = (const f4v*)(part4 + gid);
    f4v s = __builtin_nontemporal_load(p);
#pragma unroll
    for (int c = 1; c < NCH; ++c) {
        f4v v = __builtin_nontemporal_load(p + (size_t)c * (Bb * Oo / 4));
        s.x += v.x; s.y += v.y; s.z += v.z; s.w += v.w;
    }
    float4 bv = ((const float4*)bias4)[gid & 63];
    float4 o;
    o.x = s.x + bv.x; o.y = s.y + bv.y; o.z = s.z + bv.z; o.w = s.w + bv.w;
    out4[gid] = o;
}

extern "C" void kernel_launch(void* const* d_in, const int* in_sizes, int n_in,
                              void* d_out, int out_size, void* d_ws, size_t ws_size,
                              hipStream_t stream) {
    const float* x     = (const float*)d_in[0];
    const float* wbase = (const float*)d_in[1];
    const float* coeff = (const float*)d_in[2];
    const float* scale = (const float*)d_in[3];
    const float* bias  = (const float*)d_in[4];
    float* out = (float*)d_out;

    char* ws = (char*)d_ws;
    u16*    cp    = (u16*)ws;                             // 16 MB  @ 0
    float*  wt    = (float*)(ws + (16u << 20));           // 256 KB @ 16M
    float4* part4 = (float4*)(ws + (17u << 20));          // 8 MB   @ 17M

    kperm<<<1024, 256, 0, stream>>>(coeff, scale, wbase, cp, wt);
    kmain<<<1024, 256, 0, stream>>>(x, (const char*)cp, wt, part4);
    kreduce<<<(Bb * Oo / 4) / 256, 256, 0, stream>>>(part4, (const float4*)bias, (float4*)out);
}

// Round 8
// 106.205 us; speedup vs baseline: 2.7539x; 1.0328x over previous
//
#include <hip/hip_runtime.h>

// Problem constants
constexpr int Bb = 1024;   // batch
constexpr int Ii = 256;    // in features
constexpr int Oo = 256;    // out features
constexpr int Kk = 128;    // knots
constexpr int NCH = 8;     // i-chunks (XCD-aligned)

typedef unsigned short u16;
typedef unsigned int u32;
typedef u16 ushort8v __attribute__((ext_vector_type(8)));
typedef float f4v __attribute__((ext_vector_type(4)));

__device__ __forceinline__ float bf16u_to_f(u16 u) {
    union { u32 ui; float f; } c;
    c.ui = ((u32)u) << 16;
    return c.f;
}
__device__ __forceinline__ u16 f_to_bf16(float f) {  // round-to-nearest-even
    union { float f; u32 u; } c; c.f = f;
    u32 r = c.u + 0x7fffu + ((c.u >> 16) & 1u);
    return (u16)(r >> 16);
}

// Kernel A: permute+scale Cs[o][i][k] -> Cp[i][k][o] bf16 via LDS transpose.
// XCD-aligned numbering (chunk = blk & 7): chunk c's 2 MB Cp slice is written
// by XCD c and stays cache-resident for kmain's gathers (R4: kmain FETCH
// 8.9 MB vs 256 MB gather volume -> locality verified).
// cs reads non-temporal (32 MB read-once stream must not evict cp).
// Tail: blocks <256 transpose wbase -> wt (bf16: halves traffic, and
// lets kmain stage all 32 w-rows in 16 KB LDS).
// NO fences, NO atomics (R3: in-kernel device fences = L2 flush storm;
// R4: cross-XCD shared-line atomics = HBM-side RMW storm). Kernel boundary
// is the coherence point.
__global__ __launch_bounds__(256) void kperm(const float* __restrict__ cs,
                                             const float* __restrict__ scale,
                                             const float* __restrict__ wbase,
                                             u16* __restrict__ cp,
                                             u16* __restrict__ wt) {
    __shared__ u16 T[128 * 66];       // [o_local][k_local], pitch 66
    int blk = blockIdx.x;
    int chunk = blk & 7;
    int sub = blk >> 3;               // 0..127
    int i  = chunk * 32 + (sub & 31); // i within this XCD's chunk
    int oh = (sub >> 5) & 1, kh = (sub >> 6) & 1;
    int o0 = oh << 7, kb = kh << 6;
    int t = threadIdx.x;

    // Phase 1: load Cs rows (float4 along k, nt), scale, bf16 -> LDS
    {
        int c4 = t & 15;              // float4 index within the 64-k half
        int rb = t >> 4;              // 0..15
        const f4v* cs4 = (const f4v*)cs;
#pragma unroll
        for (int p = 0; p < 8; ++p) {
            int r = p * 16 + rb;      // o_local 0..127
            int o = o0 + r;
            float sc = scale[o * Ii + i];
            f4v val = __builtin_nontemporal_load(
                &cs4[(size_t)(o * Ii + i) * (Kk / 4) + kh * 16 + c4]);
            int kl = c4 * 4;
            T[r * 66 + kl + 0] = f_to_bf16(val.x * sc);
            T[r * 66 + kl + 1] = f_to_bf16(val.y * sc);
            T[r * 66 + kl + 2] = f_to_bf16(val.z * sc);
            T[r * 66 + kl + 3] = f_to_bf16(val.w * sc);
        }
    }
    __syncthreads();
    // Phase 2: write Cp[i][kb+kl][o0..o0+128], lanes <-> o (u32 = 2 o).
    {
        int og = t & 63;              // o-pair index
        int kg = t >> 6;              // 0..3, 16 k-rows each
#pragma unroll
        for (int m = 0; m < 16; ++m) {
            int kl = kg * 16 + m;
            u32 lo = T[(og * 2) * 66 + kl];
            u32 hi = T[(og * 2 + 1) * 66 + kl];
            *(u32*)&cp[((size_t)i * Kk + kb + kl) * Oo + o0 + og * 2] = lo | (hi << 16);
        }
    }
    // Tail: Wt[i][o] = bf16(W[o][i]) (65536 elems across blocks 0..255)
    if (blk < 256) {
        int gid = blk * 256 + t;
        wt[gid] = f_to_bf16(
            __builtin_nontemporal_load(&wbase[(gid & 255) * Ii + (gid >> 8)]));
    }
}

// Kernel B: main accumulation. 1024 blocks = 128 b-tiles x 8 i-chunks.
// R7: BOTH w-staging AND occupancy (R5 had staging @4 blocks/CU; R6 had
// 8 blocks/CU but un-staged w -> redundant L2 w-reads; they tied at ~110).
//   * wt is bf16 -> wbuf LDS = 16 KB; + sf 4 KB = 20 KB -> 8 blocks/CU
//     (8 x 20480 = 160 KiB exactly), 32 waves/CU latency hiding.
//   * thread = 1 b x 8 o: 2 x 16 B ushort8 gathers per i-iter; each
//     half-wave gather = contiguous 512 B row segment in the XCD-local
//     cp slice (R4: FETCH 8.9 MB vs 256 MB -> cache-hit verified).
//   * w read: 16 B/lane ds_read_b128 from wbuf, conflict-free; +8 cvt/iter.
//   * sf [bl][il] layout: conflict-free writes; one __syncthreads for wbuf.
__global__ __launch_bounds__(256, 8) void kmain(const float* __restrict__ x,
                                                const char* __restrict__ cpb,
                                                const u16* __restrict__ wt,
                                                float4* __restrict__ part4) {
    __shared__ float4 sf[256];           // [bl][il] : 8 b x 32 i    (4 KB)
    __shared__ u16 wbuf[32 * 256];       // [m][o] bf16 w rows      (16 KB)
    int t = threadIdx.x;
    int blk = blockIdx.x;
    int chunk = blk & (NCH - 1);
    int b0 = (blk >> 3) << 3;            // b-tile * 8
    int i0 = chunk << 5;                 // 32 i per chunk

    {                                    // prep: 1 (b,i) value per thread
        int il = t & 31, bl = t >> 5;    // coalesced x reads along il
        float xv = __builtin_nontemporal_load(
            &x[(size_t)(b0 + bl) * Ii + i0 + il]);
        float e2 = __expf(2.f * xv);
        float p = 1.f - 2.f / (e2 + 1.f);   // tanh
        float s = p / (1.f + __expf(-p));   // silu(p)
        float c = fminf(fmaxf(p, -1.f), 1.f);
        float scaled = (c + 1.f) * ((float)(Kk - 1) * 0.5f);
        int l = (int)floorf(scaled);
        l = min(max(l, 0), Kk - 1);
        int rr = min(l + 1, Kk - 1);
        float4 v;
        v.x = scaled - (float)l;             // frac
        v.y = s;                             // silu
        v.z = __int_as_float(l * (Oo * 2));  // byte ofs, left row in [k][o] slab
        v.w = __int_as_float(rr * (Oo * 2)); // byte ofs, right row
        sf[bl * 32 + il] = v;                // 16 B/lane stride: conflict-free
    }
    {                                    // stage 32 bf16 w-rows (16 KB)
        const ushort8v* wsrc = (const ushort8v*)(wt + (size_t)i0 * Oo);
        ushort8v* wdst = (ushort8v*)wbuf;
#pragma unroll
        for (int p = 0; p < 4; ++p)      // 1024 x 16 B chunks, coalesced
            wdst[t + p * 256] = wsrc[t + p * 256];
    }
    __syncthreads();                     // wbuf is cross-wave shared

    int oq = t & 31;                     // o = oq*8 .. oq*8+7
    int bl = t >> 5;                     // b = b0 + bl
    float a0=0.f,a1=0.f,a2=0.f,a3=0.f,a4=0.f,a5=0.f,a6=0.f,a7=0.f;
    const char* cbase = cpb + (size_t)i0 * (Kk * Oo * 2) + oq * 16;

#pragma unroll 2
    for (int m = 0; m < 32; ++m) {
        float4 v = sf[bl * 32 + m];                  // broadcast (2 addrs/wave)
        ushort8v wv = *(const ushort8v*)&wbuf[m * 256 + oq * 8];  // b128
        const char* ci = cbase + (size_t)m * (Kk * Oo * 2);
        ushort8v cl = *(const ushort8v*)(ci + __float_as_int(v.z));  // 16 B gather
        ushort8v cr = *(const ushort8v*)(ci + __float_as_int(v.w));  // 16 B gather
        float f = v.x, g = 1.f - v.x, s = v.y;
        a0 = fmaf(s, bf16u_to_f(wv[0]), a0); a1 = fmaf(s, bf16u_to_f(wv[1]), a1);
        a2 = fmaf(s, bf16u_to_f(wv[2]), a2); a3 = fmaf(s, bf16u_to_f(wv[3]), a3);
        a4 = fmaf(s, bf16u_to_f(wv[4]), a4); a5 = fmaf(s, bf16u_to_f(wv[5]), a5);
        a6 = fmaf(s, bf16u_to_f(wv[6]), a6); a7 = fmaf(s, bf16u_to_f(wv[7]), a7);
        a0 = fmaf(g, bf16u_to_f(cl[0]), a0); a0 = fmaf(f, bf16u_to_f(cr[0]), a0);
        a1 = fmaf(g, bf16u_to_f(cl[1]), a1); a1 = fmaf(f, bf16u_to_f(cr[1]), a1);
        a2 = fmaf(g, bf16u_to_f(cl[2]), a2); a2 = fmaf(f, bf16u_to_f(cr[2]), a2);
        a3 = fmaf(g, bf16u_to_f(cl[3]), a3); a3 = fmaf(f, bf16u_to_f(cr[3]), a3);
        a4 = fmaf(g, bf16u_to_f(cl[4]), a4); a4 = fmaf(f, bf16u_to_f(cr[4]), a4);
        a5 = fmaf(g, bf16u_to_f(cl[5]), a5); a5 = fmaf(f, bf16u_to_f(cr[5]), a5);
        a6 = fmaf(g, bf16u_to_f(cl[6]), a6); a6 = fmaf(f, bf16u_to_f(cr[6]), a6);
        a7 = fmaf(g, bf16u_to_f(cl[7]), a7); a7 = fmaf(f, bf16u_to_f(cr[7]), a7);
    }

    size_t cstride = (size_t)(Bb * Oo / 4);
    float4 r0; r0.x=a0; r0.y=a1; r0.z=a2; r0.w=a3;
    float4 r1; r1.x=a4; r1.y=a5; r1.z=a6; r1.w=a7;
    size_t pb = (size_t)chunk * cstride + (size_t)(b0 + bl) * (Oo / 4) + oq * 2;
    part4[pb]     = r0;
    part4[pb + 1] = r1;
}

// Kernel C: out[b][o] = bias[o] + sum_c partial[c][b][o]. 256 blocks.
__global__ __launch_bounds__(256) void kreduce(const float4* __restrict__ part4,
                                               const float4* __restrict__ bias4,
                                               float4* __restrict__ out4) {
    int gid = blockIdx.x * 256 + threadIdx.x;     // = b*64 + o4
    const f4v* p = (const f4v*)(part4 + gid);
    f4v s = __builtin_nontemporal_load(p);
#pragma unroll
    for (int c = 1; c < NCH; ++c) {
        f4v v = __builtin_nontemporal_load(p + (size_t)c * (Bb * Oo / 4));
        s.x += v.x; s.y += v.y; s.z += v.z; s.w += v.w;
    }
    float4 bv = ((const float4*)bias4)[gid & 63];
    float4 o;
    o.x = s.x + bv.x; o.y = s.y + bv.y; o.z = s.z + bv.z; o.w = s.w + bv.w;
    out4[gid] = o;
}

extern "C" void kernel_launch(void* const* d_in, const int* in_sizes, int n_in,
                              void* d_out, int out_size, void* d_ws, size_t ws_size,
                              hipStream_t stream) {
    const float* x     = (const float*)d_in[0];
    const float* wbase = (const float*)d_in[1];
    const float* coeff = (const float*)d_in[2];
    const float* scale = (const float*)d_in[3];
    const float* bias  = (const float*)d_in[4];
    float* out = (float*)d_out;

    char* ws = (char*)d_ws;
    u16*    cp    = (u16*)ws;                             // 16 MB  @ 0
    u16*    wt    = (u16*)(ws + (16u << 20));             // 128 KB @ 16M
    float4* part4 = (float4*)(ws + (17u << 20));          // 8 MB   @ 17M

    kperm<<<1024, 256, 0, stream>>>(coeff, scale, wbase, cp, wt);
    kmain<<<1024, 256, 0, stream>>>(x, (const char*)cp, wt, part4);
    kreduce<<<(Bb * Oo / 4) / 256, 256, 0, stream>>>(part4, (const float4*)bias, (float4*)out);
}